// Round 1
// baseline (3807.133 us; speedup 1.0000x reference)
//
#include <hip/hip_runtime.h>

#define T_STEPS 512
#define BATCH   64
#define DIMS    256
#define NBLK    16   // blocks per direction
#define NDIR    2

typedef short bf16x8 __attribute__((ext_vector_type(8)));
typedef float f32x4  __attribute__((ext_vector_type(4)));

__device__ __forceinline__ unsigned short f2bf(float f) {
  union { float f; unsigned int u; } v; v.f = f;
  unsigned int b = v.u;
  return (unsigned short)((b + 0x7FFFu + ((b >> 16) & 1u)) >> 16);
}

__device__ __forceinline__ float sigm(float x) {
  return __builtin_amdgcn_rcpf(1.0f + __builtin_amdgcn_exp2f(-1.44269504f * x));
}
__device__ __forceinline__ float tanh_(float x) {
  return 1.0f - 2.0f * __builtin_amdgcn_rcpf(1.0f + __builtin_amdgcn_exp2f(2.88539008f * x));
}

__device__ __forceinline__ f32x4 bcast4(float s) {
  f32x4 v; v[0] = s; v[1] = s; v[2] = s; v[3] = s; return v;
}

// ---- prep: x (f32) -> bf16, [64][512][256] layout unchanged ----
__global__ void prep_x(const float* __restrict__ x, unsigned short* __restrict__ xbf) {
  size_t i = ((size_t)blockIdx.x * 256 + threadIdx.x) * 4;
  const float4 v = *reinterpret_cast<const float4*>(x + i);
  uint2 o;
  o.x = (unsigned)f2bf(v.x) | ((unsigned)f2bf(v.y) << 16);
  o.y = (unsigned)f2bf(v.z) | ((unsigned)f2bf(v.w) << 16);
  *reinterpret_cast<uint2*>(xbf + i) = o;
}

// ---- prep: W [512][1024] f32 -> WT [2][1024 cols][512 k] bf16 (transposed) ----
__global__ void prep_w(const float* __restrict__ Wf, const float* __restrict__ Wb,
                       unsigned short* __restrict__ WT) {
  int d = blockIdx.x >> 10, col = blockIdx.x & 1023;
  const float* W = d ? Wb : Wf;
  int k = threadIdx.x;
  WT[((size_t)(d * 1024 + col)) * 512 + k] = f2bf(W[(size_t)k * 1024 + col]);
}

// ---- persistent recurrence: 32 blocks (16/dir), W register-resident ----
__global__ __launch_bounds__(256, 1) void lstm_rec(
    const unsigned short* __restrict__ xbf,   // [64][512][256] bf16
    const unsigned short* __restrict__ WT,    // [2][1024][512] bf16
    const float* __restrict__ bias_f, const float* __restrict__ bias_b,
    const float* __restrict__ ci_f, const float* __restrict__ hi_f,
    const float* __restrict__ ci_b, const float* __restrict__ hi_b,
    const int* __restrict__ length,
    unsigned short* hbuf,   // [2 dir][2 buf][64][256] bf16
    float* hfinal,          // [2 dir][64][256] f32
    int* flags)             // [2 dir][520]
{
  const int blk = blockIdx.x;
  const int d = blk >> 4, g = blk & 15;
  const int lane = threadIdx.x & 63;
  const int wv = threadIdx.x >> 6;
  const int lhi = lane >> 4, llo = lane & 15;

  const float* bias = d ? bias_b : bias_f;
  const float* cini = d ? ci_b : ci_f;
  const float* hini = d ? hi_b : hi_f;
  int* flg = flags + d * 520;
  unsigned short* hb = hbuf + (size_t)d * (2 * BATCH * DIMS);

  const int dim = g * 16 + llo;   // owned h-dim (also MFMA N-col within tile = llo)

  // B-fragments of W, register-resident: wf[gate][kstep], kstep 0..7 = x rows, 8..15 = h rows
  bf16x8 wf[4][16];
  #pragma unroll
  for (int gate = 0; gate < 4; ++gate) {
    #pragma unroll
    for (int ks = 0; ks < 16; ++ks) {
      const unsigned short* p =
          WT + ((size_t)(d * 1024 + gate * 256 + dim)) * 512 + ks * 32 + lhi * 8;
      wf[gate][ks] = *reinterpret_cast<const bf16x8*>(p);
    }
  }
  float bs[4];
  #pragma unroll
  for (int gate = 0; gate < 4; ++gate) bs[gate] = bias[gate * 256 + dim];

  // C/D layout: row(batch) = wv*16 + lhi*4 + j, col(dim) = llo
  const int b0 = wv * 16 + lhi * 4;
  float c[4], h[4];
  int Ld[4];
  #pragma unroll
  for (int j = 0; j < 4; ++j) {
    c[j] = cini[dim]; h[j] = hini[dim]; Ld[j] = length[b0 + j];
  }

  // A layout: row(batch) = wv*16 + llo, k = kstep*32 + lhi*8 + e
  const int bx = wv * 16 + llo;
  const int Lx = length[bx];

  // init h^0 (own patch), publish
  #pragma unroll
  for (int j = 0; j < 4; ++j) hb[(b0 + j) * DIMS + dim] = f2bf(h[j]);
  __syncthreads();
  if (threadIdx.x == 0) { __threadfence(); atomicAdd(&flg[0], 1); }

  // preload x A-fragments for t=0
  bf16x8 xa[8];
  {
    const int tx0 = (d == 0) ? 0 : (Lx - 1);
    const unsigned short* xp = xbf + ((size_t)bx * T_STEPS + tx0) * DIMS + lhi * 8;
    #pragma unroll
    for (int ks = 0; ks < 8; ++ks) xa[ks] = *reinterpret_cast<const bf16x8*>(xp + ks * 32);
  }

  #pragma unroll 1
  for (int t = 0; t < T_STEPS; ++t) {
    f32x4 acc[4];
    #pragma unroll
    for (int gate = 0; gate < 4; ++gate) acc[gate] = bcast4(bs[gate]);

    // x-part (independent of h^t): overlaps waiting on stragglers
    #pragma unroll
    for (int ks = 0; ks < 8; ++ks) {
      #pragma unroll
      for (int gate = 0; gate < 4; ++gate)
        acc[gate] = __builtin_amdgcn_mfma_f32_16x16x32_bf16(xa[ks], wf[gate][ks], acc[gate], 0, 0, 0);
    }

    // wait for h^t
    if (lane == 0) {
      while (__hip_atomic_load(&flg[t], __ATOMIC_RELAXED, __HIP_MEMORY_SCOPE_AGENT) < NBLK) {}
    }
    __threadfence();   // acquire: invalidate L1/L2 so hbuf reads are fresh (cross-XCD safe)

    const unsigned short* hp = hb + (size_t)(t & 1) * (BATCH * DIMS) + bx * DIMS + lhi * 8;
    bf16x8 ha[8];
    #pragma unroll
    for (int ks = 0; ks < 8; ++ks) ha[ks] = *reinterpret_cast<const bf16x8*>(hp + ks * 32);
    #pragma unroll
    for (int ks = 0; ks < 8; ++ks) {
      #pragma unroll
      for (int gate = 0; gate < 4; ++gate)
        acc[gate] = __builtin_amdgcn_mfma_f32_16x16x32_bf16(ha[ks], wf[gate][ks + 8], acc[gate], 0, 0, 0);
    }

    // prefetch x A-fragments for t+1 (hides xbf latency under epilogue+sync)
    if (t + 1 < T_STEPS) {
      const int tn = t + 1;
      const int tx = (d == 0) ? tn : ((tn < Lx) ? (Lx - 1 - tn) : tn);
      const unsigned short* xp = xbf + ((size_t)bx * T_STEPS + tx) * DIMS + lhi * 8;
      #pragma unroll
      for (int ks = 0; ks < 8; ++ks) xa[ks] = *reinterpret_cast<const bf16x8*>(xp + ks * 32);
    }

    // gate order (cudnn-compatible): i, g, f, o
    unsigned short* hw = hb + (size_t)((t + 1) & 1) * (BATCH * DIMS);
    #pragma unroll
    for (int j = 0; j < 4; ++j) {
      const float gi = acc[0][j], gg = acc[1][j], gf = acc[2][j], go = acc[3][j];
      const float cn = sigm(gf) * c[j] + sigm(gi) * tanh_(gg);
      const float hn = tanh_(cn) * sigm(go);
      if (t < Ld[j]) { c[j] = cn; h[j] = hn; }   // freeze at t >= length
      hw[(b0 + j) * DIMS + dim] = f2bf(h[j]);
    }

    __syncthreads();
    if (threadIdx.x == 0) { __threadfence(); atomicAdd(&flg[t + 1], 1); }
  }

  // final frozen h in f32
  #pragma unroll
  for (int j = 0; j < 4; ++j)
    hfinal[((size_t)d * BATCH + b0 + j) * DIMS + dim] = h[j];
}

// ---- out[64,256] = concat(h_f, h_b) @ W_fc[512,256], f32 ----
__global__ void final_gemm(const float* __restrict__ hfinal, const float* __restrict__ Wfc,
                           float* __restrict__ out) {
  __shared__ float hrow[512];
  const int b = blockIdx.x, col = threadIdx.x;
  hrow[col]       = hfinal[(size_t)b * DIMS + col];
  hrow[256 + col] = hfinal[(size_t)(BATCH + b) * DIMS + col];
  __syncthreads();
  float acc = 0.f;
  #pragma unroll 8
  for (int k = 0; k < 512; ++k) acc = fmaf(hrow[k], Wfc[(size_t)k * DIMS + col], acc);
  out[(size_t)b * DIMS + col] = acc;
}

extern "C" void kernel_launch(void* const* d_in, const int* in_sizes, int n_in,
                              void* d_out, int out_size, void* d_ws, size_t ws_size,
                              hipStream_t stream) {
  const float* x        = (const float*)d_in[0];
  const int*   length   = (const int*)d_in[1];
  const float* W_f      = (const float*)d_in[2];
  const float* b_f      = (const float*)d_in[3];
  const float* W_b      = (const float*)d_in[4];
  const float* b_b      = (const float*)d_in[5];
  const float* c_init_f = (const float*)d_in[6];
  const float* h_init_f = (const float*)d_in[7];
  const float* c_init_b = (const float*)d_in[8];
  const float* h_init_b = (const float*)d_in[9];
  const float* W_fc     = (const float*)d_in[10];
  float* out = (float*)d_out;

  char* ws = (char*)d_ws;
  unsigned short* xbf = (unsigned short*)(ws);                       // 16,777,216 B
  unsigned short* WT  = (unsigned short*)(ws + 16777216);            //  2,097,152 B
  unsigned short* hbf = (unsigned short*)(ws + 16777216 + 2097152);  //    131,072 B
  float* hfinal       = (float*)(ws + 16777216 + 2097152 + 131072);  //    131,072 B
  int*   flags        = (int*)(ws + 16777216 + 2097152 + 131072 + 131072);

  hipMemsetAsync(flags, 0, NDIR * 520 * sizeof(int), stream);
  prep_x<<<8192, 256, 0, stream>>>(x, xbf);
  prep_w<<<2048, 512, 0, stream>>>(W_f, W_b, WT);
  lstm_rec<<<NBLK * NDIR, 256, 0, stream>>>(xbf, WT, b_f, b_b,
                                            c_init_f, h_init_f, c_init_b, h_init_b,
                                            length, hbf, hfinal, flags);
  final_gemm<<<BATCH, 256, 0, stream>>>(hfinal, W_fc, out);
}

// Round 2
// 3651.920 us; speedup vs baseline: 1.0425x; 1.0425x over previous
//
#include <hip/hip_runtime.h>

#define T_STEPS 512
#define BATCH   64
#define DIMS    256
#define NBLK    16   // blocks per direction
#define NDIR    2

typedef short bf16x8 __attribute__((ext_vector_type(8)));
typedef float f32x4  __attribute__((ext_vector_type(4)));

__device__ __forceinline__ unsigned short f2bf(float f) {
  union { float f; unsigned int u; } v; v.f = f;
  unsigned int b = v.u;
  return (unsigned short)((b + 0x7FFFu + ((b >> 16) & 1u)) >> 16);
}

__device__ __forceinline__ float sigm(float x) {
  return __builtin_amdgcn_rcpf(1.0f + __builtin_amdgcn_exp2f(-1.44269504f * x));
}
__device__ __forceinline__ float tanh_(float x) {
  return 1.0f - 2.0f * __builtin_amdgcn_rcpf(1.0f + __builtin_amdgcn_exp2f(2.88539008f * x));
}

__device__ __forceinline__ f32x4 bcast4(float s) {
  f32x4 v; v[0] = s; v[1] = s; v[2] = s; v[3] = s; return v;
}

// ---- prep: x (f32) -> bf16, [64][512][256] layout unchanged ----
__global__ void prep_x(const float* __restrict__ x, unsigned short* __restrict__ xbf) {
  size_t i = ((size_t)blockIdx.x * 256 + threadIdx.x) * 4;
  const float4 v = *reinterpret_cast<const float4*>(x + i);
  uint2 o;
  o.x = (unsigned)f2bf(v.x) | ((unsigned)f2bf(v.y) << 16);
  o.y = (unsigned)f2bf(v.z) | ((unsigned)f2bf(v.w) << 16);
  *reinterpret_cast<uint2*>(xbf + i) = o;
}

// ---- prep: W [512][1024] f32 -> WT [2][1024 cols][512 k] bf16 (transposed) ----
__global__ void prep_w(const float* __restrict__ Wf, const float* __restrict__ Wb,
                       unsigned short* __restrict__ WT) {
  int d = blockIdx.x >> 10, col = blockIdx.x & 1023;
  const float* W = d ? Wb : Wf;
  int k = threadIdx.x;
  WT[((size_t)(d * 1024 + col)) * 512 + k] = f2bf(W[(size_t)k * 1024 + col]);
}

// ---- persistent recurrence: 32 blocks (16/dir), W register-resident ----
// Waves are fully decoupled: wave w (batch rows 16w..16w+15) syncs only with
// wave w of the other 15 blocks of its direction, via per-(dir,wave,block)
// monotonic step-counter slots. All cross-block data moves through agent-scope
// relaxed atomics (cache-bypassing, no L2 invalidation anywhere in the loop).
__global__ __launch_bounds__(256, 1) void lstm_rec(
    const unsigned short* __restrict__ xbf,   // [64][512][256] bf16
    const unsigned short* __restrict__ WT,    // [2][1024][512] bf16
    const float* __restrict__ bias_f, const float* __restrict__ bias_b,
    const float* __restrict__ ci_f, const float* __restrict__ hi_f,
    const float* __restrict__ ci_b, const float* __restrict__ hi_b,
    const int* __restrict__ length,
    unsigned short* hbuf,   // [2 dir][2 buf][64][256] bf16
    float* hfinal,          // [2 dir][64][256] f32
    int* slots)             // [2 dir][4 wave][16 blk], 64B per (dir,wave) line
{
  const int blk = blockIdx.x;
  const int d = blk >> 4, g = blk & 15;
  const int lane = threadIdx.x & 63;
  const int wv = threadIdx.x >> 6;
  const int lhi = lane >> 4, llo = lane & 15;

  const float* bias = d ? bias_b : bias_f;
  const float* cini = d ? ci_b : ci_f;
  const float* hini = d ? hi_b : hi_f;
  unsigned short* hb = hbuf + (size_t)d * (2 * BATCH * DIMS);
  int* grp = slots + (d * 4 + wv) * 16;   // this wave's 16-slot sync line

  const int dim = g * 16 + llo;   // owned h-dim (MFMA N-col within tile = llo)

  // B-fragments of W, register-resident: wf[gate][kstep], ks 0..7 = x rows, 8..15 = h rows
  bf16x8 wf[4][16];
  #pragma unroll
  for (int gate = 0; gate < 4; ++gate) {
    #pragma unroll
    for (int ks = 0; ks < 16; ++ks) {
      const unsigned short* p =
          WT + ((size_t)(d * 1024 + gate * 256 + dim)) * 512 + ks * 32 + lhi * 8;
      wf[gate][ks] = *reinterpret_cast<const bf16x8*>(p);
    }
  }
  float bs[4];
  #pragma unroll
  for (int gate = 0; gate < 4; ++gate) bs[gate] = bias[gate * 256 + dim];

  // C/D layout: row(batch) = wv*16 + lhi*4 + j, col(dim) = llo
  const int b0 = wv * 16 + lhi * 4;
  float c[4], h[4];
  int Ld[4];
  #pragma unroll
  for (int j = 0; j < 4; ++j) {
    c[j] = cini[dim]; h[j] = hini[dim]; Ld[j] = length[b0 + j];
  }

  // A layout: row(batch) = wv*16 + llo, k = kstep*32 + lhi*8 + e
  const int bx = wv * 16 + llo;
  const int Lx = length[bx];

  // publish h^0 (own patch) into parity-0 buffer, then slot <- 1 ("h^0 ready")
  #pragma unroll
  for (int j = 0; j < 4; ++j)
    __hip_atomic_store(&hb[(b0 + j) * DIMS + dim], f2bf(h[j]),
                       __ATOMIC_RELAXED, __HIP_MEMORY_SCOPE_AGENT);
  if (lane == 0)
    __hip_atomic_store(&grp[g], 1, __ATOMIC_RELEASE, __HIP_MEMORY_SCOPE_AGENT);

  // preload x A-fragments for t=0 (normal cached loads)
  bf16x8 xa[8];
  {
    const int tx0 = (d == 0) ? 0 : (Lx - 1);
    const unsigned short* xp = xbf + ((size_t)bx * T_STEPS + tx0) * DIMS + lhi * 8;
    #pragma unroll
    for (int ks = 0; ks < 8; ++ks) xa[ks] = *reinterpret_cast<const bf16x8*>(xp + ks * 32);
  }

  union HA { bf16x8 v; unsigned int u[4]; };

  #pragma unroll 1
  for (int t = 0; t < T_STEPS; ++t) {
    f32x4 acc[4];
    #pragma unroll
    for (int gate = 0; gate < 4; ++gate) acc[gate] = bcast4(bs[gate]);

    // x-part (independent of h^t): overlaps straggler wait
    #pragma unroll
    for (int ks = 0; ks < 8; ++ks) {
      #pragma unroll
      for (int gate = 0; gate < 4; ++gate)
        acc[gate] = __builtin_amdgcn_mfma_f32_16x16x32_bf16(xa[ks], wf[gate][ks], acc[gate], 0, 0, 0);
    }

    // wait until all 16 blocks of this (dir,wave) group published h^t
    {
      bool ok;
      do {
        int s = __hip_atomic_load(&grp[lane & 15], __ATOMIC_RELAXED, __HIP_MEMORY_SCOPE_AGENT);
        ok = (s >= t + 1);
      } while (!__all(ok));
    }
    asm volatile("" ::: "memory");   // pin: h loads stay after the poll

    // h^t A-fragments via cache-bypassing dword loads (fresh from MALL)
    const unsigned int* hp = reinterpret_cast<const unsigned int*>(
        hb + (size_t)(t & 1) * (BATCH * DIMS) + bx * DIMS + lhi * 8);
    HA ha[8];
    #pragma unroll
    for (int ks = 0; ks < 8; ++ks) {
      #pragma unroll
      for (int q = 0; q < 4; ++q)
        ha[ks].u[q] = __hip_atomic_load(hp + ks * 16 + q,
                                        __ATOMIC_RELAXED, __HIP_MEMORY_SCOPE_AGENT);
    }
    #pragma unroll
    for (int ks = 0; ks < 8; ++ks) {
      #pragma unroll
      for (int gate = 0; gate < 4; ++gate)
        acc[gate] = __builtin_amdgcn_mfma_f32_16x16x32_bf16(ha[ks].v, wf[gate][ks + 8], acc[gate], 0, 0, 0);
    }

    // prefetch x A-fragments for t+1 (overlaps epilogue; drained by the release)
    if (t + 1 < T_STEPS) {
      const int tn = t + 1;
      const int tx = (d == 0) ? tn : ((tn < Lx) ? (Lx - 1 - tn) : tn);
      const unsigned short* xp = xbf + ((size_t)bx * T_STEPS + tx) * DIMS + lhi * 8;
      #pragma unroll
      for (int ks = 0; ks < 8; ++ks) xa[ks] = *reinterpret_cast<const bf16x8*>(xp + ks * 32);
    }

    // gate order (cudnn-compatible): i, g, f, o
    unsigned short* hw = hb + (size_t)((t + 1) & 1) * (BATCH * DIMS);
    #pragma unroll
    for (int j = 0; j < 4; ++j) {
      const float gi = acc[0][j], gg = acc[1][j], gf = acc[2][j], go = acc[3][j];
      const float cn = sigm(gf) * c[j] + sigm(gi) * tanh_(gg);
      const float hn = tanh_(cn) * sigm(go);
      if (t < Ld[j]) { c[j] = cn; h[j] = hn; }   // freeze at t >= length
      __hip_atomic_store(&hw[(b0 + j) * DIMS + dim], f2bf(h[j]),
                         __ATOMIC_RELAXED, __HIP_MEMORY_SCOPE_AGENT);
    }

    // publish: release drains the wave's write-through stores, then slot <- t+2
    if (lane == 0)
      __hip_atomic_store(&grp[g], t + 2, __ATOMIC_RELEASE, __HIP_MEMORY_SCOPE_AGENT);
  }

  // final frozen h in f32
  #pragma unroll
  for (int j = 0; j < 4; ++j)
    hfinal[((size_t)d * BATCH + b0 + j) * DIMS + dim] = h[j];
}

// ---- out[64,256] = concat(h_f, h_b) @ W_fc[512,256], f32 ----
__global__ void final_gemm(const float* __restrict__ hfinal, const float* __restrict__ Wfc,
                           float* __restrict__ out) {
  __shared__ float hrow[512];
  const int b = blockIdx.x, col = threadIdx.x;
  hrow[col]       = hfinal[(size_t)b * DIMS + col];
  hrow[256 + col] = hfinal[(size_t)(BATCH + b) * DIMS + col];
  __syncthreads();
  float acc = 0.f;
  #pragma unroll 8
  for (int k = 0; k < 512; ++k) acc = fmaf(hrow[k], Wfc[(size_t)k * DIMS + col], acc);
  out[(size_t)b * DIMS + col] = acc;
}

extern "C" void kernel_launch(void* const* d_in, const int* in_sizes, int n_in,
                              void* d_out, int out_size, void* d_ws, size_t ws_size,
                              hipStream_t stream) {
  const float* x        = (const float*)d_in[0];
  const int*   length   = (const int*)d_in[1];
  const float* W_f      = (const float*)d_in[2];
  const float* b_f      = (const float*)d_in[3];
  const float* W_b      = (const float*)d_in[4];
  const float* b_b      = (const float*)d_in[5];
  const float* c_init_f = (const float*)d_in[6];
  const float* h_init_f = (const float*)d_in[7];
  const float* c_init_b = (const float*)d_in[8];
  const float* h_init_b = (const float*)d_in[9];
  const float* W_fc     = (const float*)d_in[10];
  float* out = (float*)d_out;

  char* ws = (char*)d_ws;
  unsigned short* xbf = (unsigned short*)(ws);                       // 16,777,216 B
  unsigned short* WT  = (unsigned short*)(ws + 16777216);            //  2,097,152 B
  unsigned short* hbf = (unsigned short*)(ws + 16777216 + 2097152);  //    131,072 B
  float* hfinal       = (float*)(ws + 16777216 + 2097152 + 131072);  //    131,072 B
  int*   slots        = (int*)(ws + 16777216 + 2097152 + 131072 + 131072);  // 512 B

  hipMemsetAsync(slots, 0, NDIR * 4 * NBLK * sizeof(int), stream);
  prep_x<<<8192, 256, 0, stream>>>(x, xbf);
  prep_w<<<2048, 512, 0, stream>>>(W_f, W_b, WT);
  lstm_rec<<<NBLK * NDIR, 256, 0, stream>>>(xbf, WT, b_f, b_b,
                                            c_init_f, h_init_f, c_init_b, h_init_b,
                                            length, hbf, hfinal, slots);
  final_gemm<<<BATCH, 256, 0, stream>>>(hfinal, W_fc, out);
}

// Round 3
// 2450.774 us; speedup vs baseline: 1.5534x; 1.4901x over previous
//
#include <hip/hip_runtime.h>

#define T_STEPS 512
#define BATCH   64
#define DIMS    256
#define NBLK    16   // blocks per direction
#define NDIR    2

typedef short bf16x8 __attribute__((ext_vector_type(8)));
typedef float f32x4  __attribute__((ext_vector_type(4)));

__device__ __forceinline__ unsigned short f2bf(float f) {
  union { float f; unsigned int u; } v; v.f = f;
  unsigned int b = v.u;
  return (unsigned short)((b + 0x7FFFu + ((b >> 16) & 1u)) >> 16);
}

__device__ __forceinline__ float sigm(float x) {
  return __builtin_amdgcn_rcpf(1.0f + __builtin_amdgcn_exp2f(-1.44269504f * x));
}
__device__ __forceinline__ float tanh_(float x) {
  return 1.0f - 2.0f * __builtin_amdgcn_rcpf(1.0f + __builtin_amdgcn_exp2f(2.88539008f * x));
}

__device__ __forceinline__ f32x4 bcast4(float s) {
  f32x4 v; v[0] = s; v[1] = s; v[2] = s; v[3] = s; return v;
}

// ---- prep: x (f32) -> bf16, [64][512][256] layout unchanged ----
__global__ void prep_x(const float* __restrict__ x, unsigned short* __restrict__ xbf) {
  size_t i = ((size_t)blockIdx.x * 256 + threadIdx.x) * 4;
  const float4 v = *reinterpret_cast<const float4*>(x + i);
  uint2 o;
  o.x = (unsigned)f2bf(v.x) | ((unsigned)f2bf(v.y) << 16);
  o.y = (unsigned)f2bf(v.z) | ((unsigned)f2bf(v.w) << 16);
  *reinterpret_cast<uint2*>(xbf + i) = o;
}

// ---- prep: W [512][1024] f32 -> WT [2][1024 cols][512 k] bf16 (transposed) ----
__global__ void prep_w(const float* __restrict__ Wf, const float* __restrict__ Wb,
                       unsigned short* __restrict__ WT) {
  int d = blockIdx.x >> 10, col = blockIdx.x & 1023;
  const float* W = d ? Wb : Wf;
  int k = threadIdx.x;
  WT[((size_t)(d * 1024 + col)) * 512 + k] = f2bf(W[(size_t)k * 1024 + col]);
}

// ---- persistent recurrence: 32 blocks (16/dir), W register-resident (forced) ----
__global__ __launch_bounds__(256, 1) void lstm_rec(
    const unsigned short* __restrict__ xbf,   // [64][512][256] bf16
    const unsigned short* __restrict__ WT,    // [2][1024][512] bf16
    const float* __restrict__ bias_f, const float* __restrict__ bias_b,
    const float* __restrict__ ci_f, const float* __restrict__ hi_f,
    const float* __restrict__ ci_b, const float* __restrict__ hi_b,
    const int* __restrict__ length,
    unsigned short* hbuf,   // [2 dir][2 buf][64][256] bf16
    float* hfinal,          // [2 dir][64][256] f32
    int* counters)          // [2 dir][4 wave] packed step counters, 64B-strided
{
  const int blk = blockIdx.x;
  const int d = blk >> 4, g = blk & 15;
  const int lane = threadIdx.x & 63;
  const int wv = threadIdx.x >> 6;
  const int lhi = lane >> 4, llo = lane & 15;

  const float* bias = d ? bias_b : bias_f;
  const float* cini = d ? ci_b : ci_f;
  const float* hini = d ? hi_b : hi_f;
  unsigned short* hb = hbuf + (size_t)d * (2 * BATCH * DIMS);
  int* cnt = counters + (d * 4 + wv) * 16;   // one 64B line per (dir,wave) group

  const int dim = g * 16 + llo;   // owned h-dim (MFMA N-col within tile = llo)

  // B-fragments of W: wf[gate][kstep], ks 0..7 = x rows, 8..15 = h rows.
  // KEEP: value becomes output of a volatile asm -> compiler cannot
  // rematerialize the load inside the loop; forces true register residency.
  bf16x8 wf[4][16];
  #pragma unroll
  for (int gate = 0; gate < 4; ++gate) {
    #pragma unroll
    for (int ks = 0; ks < 16; ++ks) {
      const unsigned short* p =
          WT + ((size_t)(d * 1024 + gate * 256 + dim)) * 512 + ks * 32 + lhi * 8;
      wf[gate][ks] = *reinterpret_cast<const bf16x8*>(p);
      asm volatile("" : "+v"(wf[gate][ks]));
    }
  }
  float bs[4];
  #pragma unroll
  for (int gate = 0; gate < 4; ++gate) bs[gate] = bias[gate * 256 + dim];

  // C/D layout: row(batch) = wv*16 + lhi*4 + j, col(dim) = llo
  const int b0 = wv * 16 + lhi * 4;
  float c[4], h[4];
  int Ld[4];
  #pragma unroll
  for (int j = 0; j < 4; ++j) {
    c[j] = cini[dim]; h[j] = hini[dim]; Ld[j] = length[b0 + j];
  }

  // A layout: row(batch) = wv*16 + llo, k = kstep*32 + lhi*8 + e
  const int bx = wv * 16 + llo;
  const int Lx = length[bx];

  // publish h^0 (own patch) into parity-0 buffer, then counter += 1
  #pragma unroll
  for (int j = 0; j < 4; ++j)
    __hip_atomic_store(&hb[(b0 + j) * DIMS + dim], f2bf(h[j]),
                       __ATOMIC_RELAXED, __HIP_MEMORY_SCOPE_AGENT);
  if (lane == 0)
    __hip_atomic_fetch_add(cnt, 1, __ATOMIC_RELEASE, __HIP_MEMORY_SCOPE_AGENT);

  // preload x A-fragments for t=0 (normal cached loads)
  bf16x8 xa[8];
  {
    const int tx0 = (d == 0) ? 0 : (Lx - 1);
    const unsigned short* xp = xbf + ((size_t)bx * T_STEPS + tx0) * DIMS + lhi * 8;
    #pragma unroll
    for (int ks = 0; ks < 8; ++ks) xa[ks] = *reinterpret_cast<const bf16x8*>(xp + ks * 32);
  }

  #pragma unroll 1
  for (int t = 0; t < T_STEPS; ++t) {
    f32x4 acc[4];
    #pragma unroll
    for (int gate = 0; gate < 4; ++gate) acc[gate] = bcast4(bs[gate]);

    // x-part (independent of h^t): runs while other blocks finish step t-1
    #pragma unroll
    for (int ks = 0; ks < 8; ++ks) {
      #pragma unroll
      for (int gate = 0; gate < 4; ++gate)
        acc[gate] = __builtin_amdgcn_mfma_f32_16x16x32_bf16(xa[ks], wf[gate][ks], acc[gate], 0, 0, 0);
    }

    // wait until all 16 blocks of this (dir,wave) group published h^t
    {
      const int target = 16 * (t + 1);
      while (__hip_atomic_load(cnt, __ATOMIC_RELAXED, __HIP_MEMORY_SCOPE_AGENT) < target) {}
    }

    // h^t A-fragments: 8x cache-bypassing 16B loads (fresh from MALL)
    const unsigned short* hrd =
        hb + (size_t)(t & 1) * (BATCH * DIMS) + bx * DIMS + lhi * 8;
    bf16x8 ha[8];
    #pragma unroll
    for (int ks = 0; ks < 8; ++ks)
      asm volatile("global_load_dwordx4 %0, %1, off sc0 sc1"
                   : "=v"(ha[ks]) : "v"(hrd + ks * 32) : "memory");
    asm volatile("s_waitcnt vmcnt(0)" ::: "memory");
    __builtin_amdgcn_sched_barrier(0);

    // prefetch x A-fragments for t+1 (cached; latency hidden under h-MFMAs,
    // drained by the release RMW's vmcnt(0))
    if (t + 1 < T_STEPS) {
      const int tn = t + 1;
      const int tx = (d == 0) ? tn : ((tn < Lx) ? (Lx - 1 - tn) : tn);
      const unsigned short* xp = xbf + ((size_t)bx * T_STEPS + tx) * DIMS + lhi * 8;
      #pragma unroll
      for (int ks = 0; ks < 8; ++ks) xa[ks] = *reinterpret_cast<const bf16x8*>(xp + ks * 32);
    }

    #pragma unroll
    for (int ks = 0; ks < 8; ++ks) {
      #pragma unroll
      for (int gate = 0; gate < 4; ++gate)
        acc[gate] = __builtin_amdgcn_mfma_f32_16x16x32_bf16(ha[ks], wf[gate][ks + 8], acc[gate], 0, 0, 0);
    }

    // gate order (cudnn-compatible): i, g, f, o
    unsigned short* hw = hb + (size_t)((t + 1) & 1) * (BATCH * DIMS);
    #pragma unroll
    for (int j = 0; j < 4; ++j) {
      const float gi = acc[0][j], gg = acc[1][j], gf = acc[2][j], go = acc[3][j];
      const float cn = sigm(gf) * c[j] + sigm(gi) * tanh_(gg);
      const float hn = tanh_(cn) * sigm(go);
      if (t < Ld[j]) { c[j] = cn; h[j] = hn; }   // freeze at t >= length
      __hip_atomic_store(&hw[(b0 + j) * DIMS + dim], f2bf(h[j]),
                         __ATOMIC_RELAXED, __HIP_MEMORY_SCOPE_AGENT);
    }

    // publish: RELEASE fetch_add drains this wave's stores (vmcnt(0)), then bumps
    if (lane == 0)
      __hip_atomic_fetch_add(cnt, 1, __ATOMIC_RELEASE, __HIP_MEMORY_SCOPE_AGENT);
  }

  // final frozen h in f32
  #pragma unroll
  for (int j = 0; j < 4; ++j)
    hfinal[((size_t)d * BATCH + b0 + j) * DIMS + dim] = h[j];
}

// ---- out[64,256] = concat(h_f, h_b) @ W_fc[512,256], f32 ----
__global__ void final_gemm(const float* __restrict__ hfinal, const float* __restrict__ Wfc,
                           float* __restrict__ out) {
  __shared__ float hrow[512];
  const int b = blockIdx.x, col = threadIdx.x;
  hrow[col]       = hfinal[(size_t)b * DIMS + col];
  hrow[256 + col] = hfinal[(size_t)(BATCH + b) * DIMS + col];
  __syncthreads();
  float acc = 0.f;
  #pragma unroll 8
  for (int k = 0; k < 512; ++k) acc = fmaf(hrow[k], Wfc[(size_t)k * DIMS + col], acc);
  out[(size_t)b * DIMS + col] = acc;
}

extern "C" void kernel_launch(void* const* d_in, const int* in_sizes, int n_in,
                              void* d_out, int out_size, void* d_ws, size_t ws_size,
                              hipStream_t stream) {
  const float* x        = (const float*)d_in[0];
  const int*   length   = (const int*)d_in[1];
  const float* W_f      = (const float*)d_in[2];
  const float* b_f      = (const float*)d_in[3];
  const float* W_b      = (const float*)d_in[4];
  const float* b_b      = (const float*)d_in[5];
  const float* c_init_f = (const float*)d_in[6];
  const float* h_init_f = (const float*)d_in[7];
  const float* c_init_b = (const float*)d_in[8];
  const float* h_init_b = (const float*)d_in[9];
  const float* W_fc     = (const float*)d_in[10];
  float* out = (float*)d_out;

  char* ws = (char*)d_ws;
  unsigned short* xbf = (unsigned short*)(ws);                       // 16,777,216 B
  unsigned short* WT  = (unsigned short*)(ws + 16777216);            //  2,097,152 B
  unsigned short* hbf = (unsigned short*)(ws + 16777216 + 2097152);  //    131,072 B
  float* hfinal       = (float*)(ws + 16777216 + 2097152 + 131072);  //    131,072 B
  int*   counters     = (int*)(ws + 16777216 + 2097152 + 131072 + 131072);  // 512 B

  hipMemsetAsync(counters, 0, NDIR * 4 * 16 * sizeof(int), stream);
  prep_x<<<8192, 256, 0, stream>>>(x, xbf);
  prep_w<<<2048, 512, 0, stream>>>(W_f, W_b, WT);
  lstm_rec<<<NBLK * NDIR, 256, 0, stream>>>(xbf, WT, b_f, b_b,
                                            c_init_f, h_init_f, c_init_b, h_init_b,
                                            length, hbf, hfinal, counters);
  final_gemm<<<BATCH, 256, 0, stream>>>(hfinal, W_fc, out);
}

// Round 4
// 2093.613 us; speedup vs baseline: 1.8185x; 1.1706x over previous
//
#include <hip/hip_runtime.h>

#define T_STEPS 512
#define BATCH   64
#define DIMS    256
#define NBLK    16   // blocks per direction
#define NDIR    2

typedef short bf16x8 __attribute__((ext_vector_type(8)));
typedef float f32x4  __attribute__((ext_vector_type(4)));
typedef unsigned int u32x4 __attribute__((ext_vector_type(4)));

__device__ __forceinline__ unsigned short f2bf(float f) {
  union { float f; unsigned int u; } v; v.f = f;
  unsigned int b = v.u;
  return (unsigned short)((b + 0x7FFFu + ((b >> 16) & 1u)) >> 16);
}

__device__ __forceinline__ float sigm(float x) {
  return __builtin_amdgcn_rcpf(1.0f + __builtin_amdgcn_exp2f(-1.44269504f * x));
}
__device__ __forceinline__ float tanh_(float x) {
  return 1.0f - 2.0f * __builtin_amdgcn_rcpf(1.0f + __builtin_amdgcn_exp2f(2.88539008f * x));
}

__device__ __forceinline__ f32x4 bcast4(float s) {
  f32x4 v; v[0] = s; v[1] = s; v[2] = s; v[3] = s; return v;
}

// ---- prep: x (f32) -> bf16, [64][512][256] layout unchanged ----
__global__ void prep_x(const float* __restrict__ x, unsigned short* __restrict__ xbf) {
  size_t i = ((size_t)blockIdx.x * 256 + threadIdx.x) * 4;
  const float4 v = *reinterpret_cast<const float4*>(x + i);
  uint2 o;
  o.x = (unsigned)f2bf(v.x) | ((unsigned)f2bf(v.y) << 16);
  o.y = (unsigned)f2bf(v.z) | ((unsigned)f2bf(v.w) << 16);
  *reinterpret_cast<uint2*>(xbf + i) = o;
}

// ---- prep: W [512][1024] f32 -> WT [2][1024 cols][512 k] bf16 (transposed) ----
__global__ void prep_w(const float* __restrict__ Wf, const float* __restrict__ Wb,
                       unsigned short* __restrict__ WT) {
  int d = blockIdx.x >> 10, col = blockIdx.x & 1023;
  const float* W = d ? Wb : Wf;
  int k = threadIdx.x;
  WT[((size_t)(d * 1024 + col)) * 512 + k] = f2bf(W[(size_t)k * 1024 + col]);
}

// ---- persistent recurrence: 32 blocks (16/dir), W register-resident ----
// Cross-block exchange is flag-in-data: h words are uint32 (tag<<16 | bf16),
// stored sc0/sc1 (MALL-coherent, no cache maintenance). Consumers poll their
// own input slice until every word carries tag == t+1; the poll IS the load.
// No fences, no RMWs, no flag round-trip anywhere in the loop.
__global__ __launch_bounds__(256, 1) void lstm_rec(
    const unsigned short* __restrict__ xbf,   // [64][512][256] bf16
    const unsigned short* __restrict__ WT,    // [2][1024][512] bf16
    const float* __restrict__ bias_f, const float* __restrict__ bias_b,
    const float* __restrict__ ci_f, const float* __restrict__ hi_f,
    const float* __restrict__ ci_b, const float* __restrict__ hi_b,
    const int* __restrict__ length,
    unsigned int* hbuf,     // [2 dir][2 slot][64][256] u32 (tag<<16 | bf16 h)
    float* hfinal)          // [2 dir][64][256] f32
{
  const int blk = blockIdx.x;
  const int d = blk >> 4, g = blk & 15;
  const int lane = threadIdx.x & 63;
  const int wv = threadIdx.x >> 6;
  const int lhi = lane >> 4, llo = lane & 15;

  const float* bias = d ? bias_b : bias_f;
  const float* cini = d ? ci_b : ci_f;
  const float* hini = d ? hi_b : hi_f;
  unsigned int* hb = hbuf + (size_t)d * (2 * BATCH * DIMS);

  const int dim = g * 16 + llo;   // owned h-dim (MFMA N-col within tile = llo)

  // B-fragments of W: wf[gate][kstep], ks 0..7 = x rows, 8..15 = h rows.
  // Pinned via volatile asm so the loads cannot be rematerialized in-loop.
  bf16x8 wf[4][16];
  #pragma unroll
  for (int gate = 0; gate < 4; ++gate) {
    #pragma unroll
    for (int ks = 0; ks < 16; ++ks) {
      const unsigned short* p =
          WT + ((size_t)(d * 1024 + gate * 256 + dim)) * 512 + ks * 32 + lhi * 8;
      wf[gate][ks] = *reinterpret_cast<const bf16x8*>(p);
      asm volatile("" : "+v"(wf[gate][ks]));
    }
  }
  float bs[4];
  #pragma unroll
  for (int gate = 0; gate < 4; ++gate) bs[gate] = bias[gate * 256 + dim];

  // C/D layout: row(batch) = wv*16 + lhi*4 + j, col(dim) = llo
  const int b0 = wv * 16 + lhi * 4;
  float c[4], h[4];
  int Ld[4];
  #pragma unroll
  for (int j = 0; j < 4; ++j) {
    c[j] = cini[dim]; h[j] = hini[dim]; Ld[j] = length[b0 + j];
  }

  // A layout: row(batch) = wv*16 + llo, k = kstep*32 + lhi*8 + e
  const int bx = wv * 16 + llo;
  const int Lx = length[bx];

  // publish h^0 (tag=1) into slot 0
  #pragma unroll
  for (int j = 0; j < 4; ++j) {
    unsigned int val = (1u << 16) | (unsigned int)f2bf(h[j]);
    const unsigned int* ap = hb + (b0 + j) * DIMS + dim;
    asm volatile("global_store_dword %0, %1, off sc0 sc1"
                 :: "v"(ap), "v"(val) : "memory");
  }

  // preload x A-fragments for t=0 (normal cached loads)
  bf16x8 xa[8];
  {
    const int tx0 = (d == 0) ? 0 : (Lx - 1);
    const unsigned short* xp = xbf + ((size_t)bx * T_STEPS + tx0) * DIMS + lhi * 8;
    #pragma unroll
    for (int ks = 0; ks < 8; ++ks) xa[ks] = *reinterpret_cast<const bf16x8*>(xp + ks * 32);
  }

  #pragma unroll 1
  for (int t = 0; t < T_STEPS; ++t) {
    f32x4 acc[4];
    #pragma unroll
    for (int gate = 0; gate < 4; ++gate) acc[gate] = bcast4(bs[gate]);

    // x-part (independent of h^t): runs while producers finish step t-1
    #pragma unroll
    for (int ks = 0; ks < 8; ++ks) {
      #pragma unroll
      for (int gate = 0; gate < 4; ++gate)
        acc[gate] = __builtin_amdgcn_mfma_f32_16x16x32_bf16(xa[ks], wf[gate][ks], acc[gate], 0, 0, 0);
    }

    // poll own k-slice of h^t until all 64 words carry tag t+1
    const unsigned int* hr = hb + (size_t)(t & 1) * (BATCH * DIMS) + bx * DIMS + lhi * 8;
    u32x4 w[16];
    {
      const unsigned int tagsh = (unsigned int)(t + 1) << 16;
      bool ready;
      do {
        #pragma unroll
        for (int ks = 0; ks < 8; ++ks) {
          const unsigned int* p = hr + ks * 32;
          asm volatile("global_load_dwordx4 %0, %1, off sc0 sc1"
                       : "=v"(w[2 * ks]) : "v"(p) : "memory");
          asm volatile("global_load_dwordx4 %0, %1, off sc0 sc1"
                       : "=v"(w[2 * ks + 1]) : "v"(p + 4) : "memory");
        }
        asm volatile("s_waitcnt vmcnt(0)" ::: "memory");
        unsigned int bad = 0;
        #pragma unroll
        for (int i = 0; i < 16; ++i)
          #pragma unroll
          for (int q = 0; q < 4; ++q)
            bad |= (w[i][q] ^ tagsh);
        ready = ((bad >> 16) == 0);
      } while (!__all(ready));
    }
    __builtin_amdgcn_sched_barrier(0);

    // repack low halves -> bf16x8 A-fragments
    bf16x8 ha[8];
    #pragma unroll
    for (int ks = 0; ks < 8; ++ks) {
      union { bf16x8 v; unsigned int dd[4]; } u;
      u.dd[0] = (w[2 * ks][0]     & 0xFFFFu) | (w[2 * ks][1]     << 16);
      u.dd[1] = (w[2 * ks][2]     & 0xFFFFu) | (w[2 * ks][3]     << 16);
      u.dd[2] = (w[2 * ks + 1][0] & 0xFFFFu) | (w[2 * ks + 1][1] << 16);
      u.dd[3] = (w[2 * ks + 1][2] & 0xFFFFu) | (w[2 * ks + 1][3] << 16);
      ha[ks] = u.v;
    }

    // prefetch x A-fragments for t+1 (cached; drained by next poll's vmcnt)
    if (t + 1 < T_STEPS) {
      const int tn = t + 1;
      const int tx = (d == 0) ? tn : ((tn < Lx) ? (Lx - 1 - tn) : tn);
      const unsigned short* xp = xbf + ((size_t)bx * T_STEPS + tx) * DIMS + lhi * 8;
      #pragma unroll
      for (int ks = 0; ks < 8; ++ks) xa[ks] = *reinterpret_cast<const bf16x8*>(xp + ks * 32);
    }

    #pragma unroll
    for (int ks = 0; ks < 8; ++ks) {
      #pragma unroll
      for (int gate = 0; gate < 4; ++gate)
        acc[gate] = __builtin_amdgcn_mfma_f32_16x16x32_bf16(ha[ks], wf[gate][ks + 8], acc[gate], 0, 0, 0);
    }

    // gate order (cudnn-compatible): i, g, f, o — then publish h^{t+1} (tag t+2)
    unsigned int* hw = hb + (size_t)((t + 1) & 1) * (BATCH * DIMS);
    const unsigned int ptag = (unsigned int)(t + 2) << 16;
    #pragma unroll
    for (int j = 0; j < 4; ++j) {
      const float gi = acc[0][j], gg = acc[1][j], gf = acc[2][j], go = acc[3][j];
      const float cn = sigm(gf) * c[j] + sigm(gi) * tanh_(gg);
      const float hn = tanh_(cn) * sigm(go);
      if (t < Ld[j]) { c[j] = cn; h[j] = hn; }   // freeze at t >= length
      unsigned int val = ptag | (unsigned int)f2bf(h[j]);
      const unsigned int* ap = hw + (b0 + j) * DIMS + dim;
      asm volatile("global_store_dword %0, %1, off sc0 sc1"
                   :: "v"(ap), "v"(val) : "memory");
    }
  }

  // final frozen h in f32
  #pragma unroll
  for (int j = 0; j < 4; ++j)
    hfinal[((size_t)d * BATCH + b0 + j) * DIMS + dim] = h[j];
}

// ---- out[64,256] = concat(h_f, h_b) @ W_fc[512,256], f32 ----
__global__ void final_gemm(const float* __restrict__ hfinal, const float* __restrict__ Wfc,
                           float* __restrict__ out) {
  __shared__ float hrow[512];
  const int b = blockIdx.x, col = threadIdx.x;
  hrow[col]       = hfinal[(size_t)b * DIMS + col];
  hrow[256 + col] = hfinal[(size_t)(BATCH + b) * DIMS + col];
  __syncthreads();
  float acc = 0.f;
  #pragma unroll 8
  for (int k = 0; k < 512; ++k) acc = fmaf(hrow[k], Wfc[(size_t)k * DIMS + col], acc);
  out[(size_t)b * DIMS + col] = acc;
}

extern "C" void kernel_launch(void* const* d_in, const int* in_sizes, int n_in,
                              void* d_out, int out_size, void* d_ws, size_t ws_size,
                              hipStream_t stream) {
  const float* x        = (const float*)d_in[0];
  const int*   length   = (const int*)d_in[1];
  const float* W_f      = (const float*)d_in[2];
  const float* b_f      = (const float*)d_in[3];
  const float* W_b      = (const float*)d_in[4];
  const float* b_b      = (const float*)d_in[5];
  const float* c_init_f = (const float*)d_in[6];
  const float* h_init_f = (const float*)d_in[7];
  const float* c_init_b = (const float*)d_in[8];
  const float* h_init_b = (const float*)d_in[9];
  const float* W_fc     = (const float*)d_in[10];
  float* out = (float*)d_out;

  char* ws = (char*)d_ws;
  unsigned short* xbf = (unsigned short*)(ws);                       // 16,777,216 B
  unsigned short* WT  = (unsigned short*)(ws + 16777216);            //  2,097,152 B
  unsigned int*   hbf = (unsigned int*)(ws + 16777216 + 2097152);    //    524,288 B
  float* hfinal       = (float*)(ws + 16777216 + 2097152 + 524288);  //    131,072 B

  // zero tags each call (deterministic across graph replays)
  hipMemsetAsync(hbf, 0, NDIR * 2 * BATCH * DIMS * sizeof(unsigned int), stream);
  prep_x<<<8192, 256, 0, stream>>>(x, xbf);
  prep_w<<<2048, 512, 0, stream>>>(W_f, W_b, WT);
  lstm_rec<<<NBLK * NDIR, 256, 0, stream>>>(xbf, WT, b_f, b_b,
                                            c_init_f, h_init_f, c_init_b, h_init_b,
                                            length, hbf, hfinal);
  final_gemm<<<BATCH, 256, 0, stream>>>(hfinal, W_fc, out);
}